// Round 7
// baseline (556.704 us; speedup 1.0000x reference)
//
#include <hip/hip_runtime.h>

#define T_TOK 1024
#define H_DIM 1024
#define I_DIM 4096
#define NE 8

typedef __attribute__((ext_vector_type(8))) short bf16x8;
typedef __attribute__((ext_vector_type(4))) float f32x4;

__device__ __forceinline__ unsigned short f2bf(float x) {
  union { float f; unsigned u; } v; v.f = x;
  unsigned r = v.u + 0x7fffu + ((v.u >> 16) & 1u);  // RNE
  return (unsigned short)(r >> 16);
}

__device__ __forceinline__ unsigned cvt_pk_bf16(float a, float b) {
  unsigned r;
  asm("v_cvt_pk_bf16_f32 %0, %1, %2" : "=v"(r) : "v"(a), "v"(b));
  return r;
}

__device__ __forceinline__ void dma16(const void* g, void* l) {
  __builtin_amdgcn_global_load_lds(
      (const __attribute__((address_space(1))) unsigned*)g,
      (__attribute__((address_space(3))) unsigned*)l, 16, 0, 0);
}

#define WAITVM0() asm volatile("s_waitcnt vmcnt(0)" ::: "memory")

// ---------------- routing ----------------
__global__ void k_route(const float* __restrict__ gates, int* __restrict__ counts,
                        int* __restrict__ tok_idx, float* __restrict__ tok_w,
                        int* __restrict__ tok_cpy) {
  int t = blockIdx.x * blockDim.x + threadIdx.x;
  if (t >= T_TOK) return;
  float g[NE];
#pragma unroll
  for (int e = 0; e < NE; ++e) g[e] = gates[t * NE + e];
  int i1 = 0; float g1 = g[0];
#pragma unroll
  for (int e = 1; e < NE; ++e) if (g[e] > g1) { g1 = g[e]; i1 = e; }
  int i2 = -1; float g2 = -1e30f;
#pragma unroll
  for (int e = 0; e < NE; ++e) if (e != i1 && g[e] > g2) { g2 = g[e]; i2 = e; }
  float wa = 1.0f / (1.0f + expf(g2 - g1));
  float wb = 1.0f - wa;
  int s1 = atomicAdd(&counts[i1], 1);
  tok_idx[i1 * T_TOK + s1] = t; tok_w[i1 * T_TOK + s1] = wa; tok_cpy[i1 * T_TOK + s1] = 0;
  int s2 = atomicAdd(&counts[i2], 1);
  tok_idx[i2 * T_TOK + s2] = t; tok_w[i2 * T_TOK + s2] = wb; tok_cpy[i2 * T_TOK + s2] = 1;
}

// ---------------- pack ----------------
__global__ void k_pack(const float* __restrict__ hs, const int* __restrict__ counts,
                       const int* __restrict__ tok_idx, const float* __restrict__ tok_w,
                       const int* __restrict__ tok_cpy, unsigned short* __restrict__ xpack,
                       float* __restrict__ row_w, int* __restrict__ inv_row) {
  int e = blockIdx.x >> 10, slot = blockIdx.x & 1023;
  if (slot >= counts[e]) return;
  int off = 0;
#pragma unroll
  for (int i = 0; i < NE; ++i) if (i < e) off += counts[i];
  int row = off + slot;
  int tok = tok_idx[e * T_TOK + slot];
  if (threadIdx.x == 0) {
    row_w[row] = tok_w[e * T_TOK + slot];
    inv_row[tok * 2 + tok_cpy[e * T_TOK + slot]] = row;
  }
  float4 v = ((const float4*)(hs + (size_t)tok * H_DIM))[threadIdx.x];
  uint2 o; o.x = cvt_pk_bf16(v.x, v.y); o.y = cvt_pk_bf16(v.z, v.w);
  ((uint2*)(xpack + (size_t)row * H_DIM))[threadIdx.x] = o;
}

// ============ GEMM1: A in LDS (per-256K phase), B global->reg, SwiGLU ============
// block = 128 tok x 128 B-rows (64 gate + 64 up interleaved), waves 2x2 (64x64).
// 8 barriers/block total; B stream has NO syncs. grid: e(3):rbh(3):mt(3):rbl(3).
__global__ __launch_bounds__(256)
void k_gemm1(const float* __restrict__ w1, const unsigned short* __restrict__ xpack,
             const int* __restrict__ counts, unsigned short* __restrict__ act) {
  int b = blockIdx.x;
  int rbl = b & 7, mt = (b >> 3) & 7, rbh = (b >> 6) & 7, e = b >> 9;
  int rb = rbh * 8 + rbl;          // [0,64) ; XCD = rbl
  int cnt = counts[e];
  int m0 = mt * 128;
  if (m0 >= cnt) return;
  int off = 0;
#pragma unroll
  for (int k = 0; k < NE; ++k) if (k < e) off += counts[k];
  int n0 = rb * 64;                // 64 act cols per block

  __shared__ __align__(16) unsigned char AL[128 * 512];  // 64 KB: [128 tok][256 K bf16], swz

  int tid = threadIdx.x, lane = tid & 63, wid = tid >> 6;
  int wm = wid & 1, wn = wid >> 1;
  int lr = lane & 15, lg = lane >> 4;

  const float* w1e = w1 + (size_t)e * (2 * I_DIM) * H_DIM;

  // B row pointers (per-lane, fixed): r = wn*64 + nr*16 + lr
  const float* bP[4];
#pragma unroll
  for (int nr = 0; nr < 4; ++nr) {
    int grow = (nr & 1) * I_DIM + n0 + ((wn * 2 + (nr >> 1)) << 4) + lr;
    bP[nr] = w1e + (size_t)grow * H_DIM + lg * 8;
  }

  // A staging constants: thread -> (srow, swizzled chunk) ; row = j*8 + srow
  int srow = tid >> 5;                       // [0,8)
  int scol = (tid & 31) ^ srow;              // source 16B-chunk (involution w/ read swz)
  // A read constants
  int axor = lr & 7;
  int abyte[4];
#pragma unroll
  for (int mr = 0; mr < 4; ++mr) abyte[mr] = (wm * 64 + mr * 16 + lr) * 512;

  f32x4 acc[4][4];
#pragma unroll
  for (int p = 0; p < 4; ++p)
#pragma unroll
    for (int q = 0; q < 4; ++q) acc[p][q] = (f32x4){0.f, 0.f, 0.f, 0.f};

  for (int ph = 0; ph < 4; ++ph) {
    int phk = ph * 256;
    if (ph) __builtin_amdgcn_s_barrier();    // prev-phase A reads complete
#pragma unroll
    for (int j = 0; j < 16; ++j) {
      int row = j * 8 + srow;
      int gr = (m0 + row < cnt) ? (m0 + row) : 0;
      dma16(xpack + (size_t)(off + gr) * H_DIM + phk + scol * 8,
            (unsigned char*)AL + j * 4096 + tid * 16);
    }
    WAITVM0();
    __builtin_amdgcn_s_barrier();
    __builtin_amdgcn_sched_barrier(0);

#pragma unroll 2
    for (int kc = 0; kc < 4; ++kc) {
      float4 bl[2][4][2];
#pragma unroll
      for (int kk = 0; kk < 2; ++kk)
#pragma unroll
        for (int nr = 0; nr < 4; ++nr) {
          const float* p = bP[nr] + phk + kc * 64 + kk * 32;
          bl[kk][nr][0] = *(const float4*)p;
          bl[kk][nr][1] = *(const float4*)(p + 4);
        }
#pragma unroll
      for (int kk = 0; kk < 2; ++kk) {
        bf16x8 a[4];
#pragma unroll
        for (int mr = 0; mr < 4; ++mr) {
          int ch = (kc * 8 + kk * 4 + lg) ^ axor;
          a[mr] = *(const bf16x8*)(AL + abyte[mr] + ch * 16);
        }
#pragma unroll
        for (int nr = 0; nr < 4; ++nr) {
          float4 lo = bl[kk][nr][0], hi = bl[kk][nr][1];
          union { unsigned u[4]; bf16x8 v; } bb;
          bb.u[0] = cvt_pk_bf16(lo.x, lo.y); bb.u[1] = cvt_pk_bf16(lo.z, lo.w);
          bb.u[2] = cvt_pk_bf16(hi.x, hi.y); bb.u[3] = cvt_pk_bf16(hi.z, hi.w);
#pragma unroll
          for (int mr = 0; mr < 4; ++mr)
            acc[mr][nr] = __builtin_amdgcn_mfma_f32_16x16x32_bf16(a[mr], bb.v, acc[mr][nr], 0, 0, 0);
        }
      }
    }
  }

  // SwiGLU epilogue: acc[mr][2p]=gate, [2p+1]=up -> col n0 + (wn*2+p)*16 + lr
#pragma unroll
  for (int mr = 0; mr < 4; ++mr) {
#pragma unroll
    for (int p = 0; p < 2; ++p) {
      f32x4 g = acc[mr][2 * p], u = acc[mr][2 * p + 1];
      int ncol = n0 + (wn * 2 + p) * 16 + lr;
#pragma unroll
      for (int q = 0; q < 4; ++q) {
        int rl = wm * 64 + mr * 16 + lg * 4 + q;
        if (m0 + rl < cnt) {
          float gv = g[q];
          float av = gv / (1.0f + expf(-gv)) * u[q];
          act[(size_t)(off + m0 + rl) * I_DIM + ncol] = f2bf(av);
        }
      }
    }
  }
}

// ============ GEMM2: A(act) in LDS per phase, B(w2) global->reg, split-K x4 ============
// block = 128 tok x 128 h-cols, kc in [0,4) (K-chunk 1024 = 4 phases of 256).
// grid: e(3):kc(2):mt(3):rb(3) ; XCD = rb -> each XCD streams one 128-row w2 slice.
__global__ __launch_bounds__(256)
void k_gemm2(const float* __restrict__ w2, const unsigned short* __restrict__ act,
             const int* __restrict__ counts, const float* __restrict__ row_w,
             float* __restrict__ yp) {
  int b = blockIdx.x;
  int rb = b & 7, mt = (b >> 3) & 7, kc = (b >> 6) & 3, e = b >> 8;
  int cnt = counts[e];
  int m0 = mt * 128;
  if (m0 >= cnt) return;
  int off = 0;
#pragma unroll
  for (int k = 0; k < NE; ++k) if (k < e) off += counts[k];
  int n0 = rb * 128;
  int kbase = kc * 1024;

  __shared__ __align__(16) unsigned char AL[128 * 512];  // 64 KB

  int tid = threadIdx.x, lane = tid & 63, wid = tid >> 6;
  int wm = wid & 1, wn = wid >> 1;
  int lr = lane & 15, lg = lane >> 4;

  const float* w2e = w2 + (size_t)e * H_DIM * I_DIM;

  const float* bP[4];
#pragma unroll
  for (int nr = 0; nr < 4; ++nr) {
    int grow = n0 + wn * 64 + nr * 16 + lr;
    bP[nr] = w2e + (size_t)grow * I_DIM + kbase + lg * 8;
  }

  int srow = tid >> 5;
  int scol = (tid & 31) ^ srow;
  int axor = lr & 7;
  int abyte[4];
#pragma unroll
  for (int mr = 0; mr < 4; ++mr) abyte[mr] = (wm * 64 + mr * 16 + lr) * 512;

  f32x4 acc[4][4];
#pragma unroll
  for (int p = 0; p < 4; ++p)
#pragma unroll
    for (int q = 0; q < 4; ++q) acc[p][q] = (f32x4){0.f, 0.f, 0.f, 0.f};

  for (int ph = 0; ph < 4; ++ph) {
    int phk = ph * 256;
    if (ph) __builtin_amdgcn_s_barrier();
#pragma unroll
    for (int j = 0; j < 16; ++j) {
      int row = j * 8 + srow;
      int gr = (m0 + row < cnt) ? (m0 + row) : 0;
      dma16(act + (size_t)(off + gr) * I_DIM + kbase + phk + scol * 8,
            (unsigned char*)AL + j * 4096 + tid * 16);
    }
    WAITVM0();
    __builtin_amdgcn_s_barrier();
    __builtin_amdgcn_sched_barrier(0);

#pragma unroll 2
    for (int kcc = 0; kcc < 4; ++kcc) {
      float4 bl[2][4][2];
#pragma unroll
      for (int kk = 0; kk < 2; ++kk)
#pragma unroll
        for (int nr = 0; nr < 4; ++nr) {
          const float* p = bP[nr] + phk + kcc * 64 + kk * 32;
          bl[kk][nr][0] = *(const float4*)p;
          bl[kk][nr][1] = *(const float4*)(p + 4);
        }
#pragma unroll
      for (int kk = 0; kk < 2; ++kk) {
        bf16x8 a[4];
#pragma unroll
        for (int mr = 0; mr < 4; ++mr) {
          int ch = (kcc * 8 + kk * 4 + lg) ^ axor;
          a[mr] = *(const bf16x8*)(AL + abyte[mr] + ch * 16);
        }
#pragma unroll
        for (int nr = 0; nr < 4; ++nr) {
          float4 lo = bl[kk][nr][0], hi = bl[kk][nr][1];
          union { unsigned u[4]; bf16x8 v; } bb;
          bb.u[0] = cvt_pk_bf16(lo.x, lo.y); bb.u[1] = cvt_pk_bf16(lo.z, lo.w);
          bb.u[2] = cvt_pk_bf16(hi.x, hi.y); bb.u[3] = cvt_pk_bf16(hi.z, hi.w);
#pragma unroll
          for (int mr = 0; mr < 4; ++mr)
            acc[mr][nr] = __builtin_amdgcn_mfma_f32_16x16x32_bf16(a[mr], bb.v, acc[mr][nr], 0, 0, 0);
        }
      }
    }
  }

  float* ypc = yp + (size_t)kc * (2048 * H_DIM);
#pragma unroll
  for (int mr = 0; mr < 4; ++mr) {
#pragma unroll
    for (int q = 0; q < 4; ++q) {
      int rl = wm * 64 + mr * 16 + lg * 4 + q;
      if (m0 + rl >= cnt) continue;
      int grow = off + m0 + rl;
      float wgt = row_w[grow];
      float* yrow = ypc + (size_t)grow * H_DIM;
#pragma unroll
      for (int nr = 0; nr < 4; ++nr) {
        int ncol = n0 + wn * 64 + nr * 16 + lr;
        yrow[ncol] = acc[mr][nr][q] * wgt;
      }
    }
  }
}

// ---------------- combine ----------------
__global__ void k_combine(const float* __restrict__ yp, const int* __restrict__ inv_row,
                          float* __restrict__ out) {
  int t = blockIdx.x, i = threadIdx.x;
  int r0 = inv_row[2 * t], r1 = inv_row[2 * t + 1];
  float4 s = make_float4(0.f, 0.f, 0.f, 0.f);
#pragma unroll
  for (int kc = 0; kc < 4; ++kc) {
    const float4* a = (const float4*)(yp + (size_t)kc * (2048 * H_DIM) + (size_t)r0 * H_DIM);
    const float4* b = (const float4*)(yp + (size_t)kc * (2048 * H_DIM) + (size_t)r1 * H_DIM);
    float4 va = a[i], vb = b[i];
    s.x += va.x + vb.x; s.y += va.y + vb.y; s.z += va.z + vb.z; s.w += va.w + vb.w;
  }
  ((float4*)(out + (size_t)t * H_DIM))[i] = s;
}

extern "C" void kernel_launch(void* const* d_in, const int* in_sizes, int n_in,
                              void* d_out, int out_size, void* d_ws, size_t ws_size,
                              hipStream_t stream) {
  const float* hs = (const float*)d_in[0];
  const float* w1 = (const float*)d_in[1];
  const float* w2 = (const float*)d_in[2];
  const float* gates = (const float*)d_in[3];
  float* out = (float*)d_out;

  char* ws = (char*)d_ws;
  int* counts = (int*)ws;
  int* tok_idx = (int*)(ws + 4096);
  float* tok_w = (float*)(ws + 4096 + 32768);
  int* tok_cpy = (int*)(ws + 4096 + 65536);
  float* row_w = (float*)(ws + 4096 + 98304);
  int* inv_row = (int*)(ws + 4096 + 98304 + 8192);
  unsigned short* xpack = (unsigned short*)(ws + (1 << 17));   // 4 MB
  unsigned short* act = (unsigned short*)(ws + (8u << 20));    // 16 MB
  float* yp = (float*)(ws + (32u << 20));                      // 4 x 8 MB

  hipMemsetAsync(counts, 0, NE * sizeof(int), stream);
  k_route<<<dim3(4), dim3(256), 0, stream>>>(gates, counts, tok_idx, tok_w, tok_cpy);
  k_pack<<<dim3(NE * T_TOK), dim3(256), 0, stream>>>(hs, counts, tok_idx, tok_w, tok_cpy,
                                                     xpack, row_w, inv_row);
  k_gemm1<<<dim3(4096), dim3(256), 0, stream>>>(w1, xpack, counts, act);
  k_gemm2<<<dim3(2048), dim3(256), 0, stream>>>(w2, act, counts, row_w, yp);
  k_combine<<<dim3(T_TOK), dim3(256), 0, stream>>>(yp, inv_row, out);
}

// Round 9
// 282.603 us; speedup vs baseline: 1.9699x; 1.9699x over previous
//
#include <hip/hip_runtime.h>

#define T_TOK 1024
#define H_DIM 1024
#define I_DIM 4096
#define NE 8

typedef __attribute__((ext_vector_type(8))) short bf16x8;
typedef __attribute__((ext_vector_type(4))) float f32x4;

#define SB() __builtin_amdgcn_sched_barrier(0)
#define WAITVM16() asm volatile("s_waitcnt vmcnt(16)" ::: "memory")

__device__ __forceinline__ f32x4 mfma16(bf16x8 a, bf16x8 b, f32x4 c) {
  return __builtin_amdgcn_mfma_f32_16x16x32_bf16(a, b, c, 0, 0, 0);
}

__device__ __forceinline__ unsigned short f2bf(float x) {
  union { float f; unsigned u; } v; v.f = x;
  unsigned r = v.u + 0x7fffu + ((v.u >> 16) & 1u);  // RNE
  return (unsigned short)(r >> 16);
}

__device__ __forceinline__ unsigned cvt_pk_bf16(float a, float b) {
  unsigned r;
  asm("v_cvt_pk_bf16_f32 %0, %1, %2" : "=v"(r) : "v"(a), "v"(b));
  return r;
}

__device__ __forceinline__ void dma16(const void* g, void* l) {
  __builtin_amdgcn_global_load_lds(
      (const __attribute__((address_space(1))) unsigned*)g,
      (__attribute__((address_space(3))) unsigned*)l, 16, 0, 0);
}

// ---------------- routing ----------------
__global__ void k_route(const float* __restrict__ gates, int* __restrict__ counts,
                        int* __restrict__ tok_idx, float* __restrict__ tok_w,
                        int* __restrict__ tok_cpy) {
  int t = blockIdx.x * blockDim.x + threadIdx.x;
  if (t >= T_TOK) return;
  float g[NE];
#pragma unroll
  for (int e = 0; e < NE; ++e) g[e] = gates[t * NE + e];
  int i1 = 0; float g1 = g[0];
#pragma unroll
  for (int e = 1; e < NE; ++e) if (g[e] > g1) { g1 = g[e]; i1 = e; }
  int i2 = -1; float g2 = -1e30f;
#pragma unroll
  for (int e = 0; e < NE; ++e) if (e != i1 && g[e] > g2) { g2 = g[e]; i2 = e; }
  float wa = 1.0f / (1.0f + expf(g2 - g1));
  float wb = 1.0f - wa;
  int s1 = atomicAdd(&counts[i1], 1);
  tok_idx[i1 * T_TOK + s1] = t; tok_w[i1 * T_TOK + s1] = wa; tok_cpy[i1 * T_TOK + s1] = 0;
  int s2 = atomicAdd(&counts[i2], 1);
  tok_idx[i2 * T_TOK + s2] = t; tok_w[i2 * T_TOK + s2] = wb; tok_cpy[i2 * T_TOK + s2] = 1;
}

// ---------------- pack ----------------
__global__ void k_pack(const float* __restrict__ hs, const int* __restrict__ counts,
                       const int* __restrict__ tok_idx, const float* __restrict__ tok_w,
                       const int* __restrict__ tok_cpy, unsigned short* __restrict__ xpack,
                       float* __restrict__ row_w, int* __restrict__ inv_row) {
  int e = blockIdx.x >> 10, slot = blockIdx.x & 1023;
  if (slot >= counts[e]) return;
  int off = 0;
#pragma unroll
  for (int i = 0; i < NE; ++i) if (i < e) off += counts[i];
  int row = off + slot;
  int tok = tok_idx[e * T_TOK + slot];
  if (threadIdx.x == 0) {
    row_w[row] = tok_w[e * T_TOK + slot];
    inv_row[tok * 2 + tok_cpy[e * T_TOK + slot]] = row;
  }
  float4 v = ((const float4*)(hs + (size_t)tok * H_DIM))[threadIdx.x];
  uint2 o; o.x = cvt_pk_bf16(v.x, v.y); o.y = cvt_pk_bf16(v.z, v.w);
  ((uint2*)(xpack + (size_t)row * H_DIM))[threadIdx.x] = o;
}

// ======================= GEMM1 (+SwiGLU) =======================
// block = 128 tok x (64 gate + 64 up rows); 4 waves, each 128tok x (16g+16u).
// A: LDS 2x32KB (128-K phases, DMA'd, src-swizzled). B: global->reg stream,
// 4-slot prefetch, sched_barrier-fenced. One counted WAITVM(16)/phase.
__global__ __launch_bounds__(256, 2)
void k_gemm1(const float* __restrict__ w1, const unsigned short* __restrict__ xpack,
             const int* __restrict__ counts, unsigned short* __restrict__ act) {
  int b = blockIdx.x;
  int x = b & 7, mt = (b >> 3) & 7, grp = b >> 6;   // grid 4096
  int panel = grp * 8 + x;                          // [0,512)
  int e = panel >> 6, nb = panel & 63;
  int cnt = counts[e];
  int m0 = mt * 128;
  if (m0 >= cnt) return;
  int off = 0;
#pragma unroll
  for (int k = 0; k < NE; ++k) if (k < e) off += counts[k];

  __shared__ __align__(16) unsigned char AL[2][32768];

  int tid = threadIdx.x, lane = tid & 63, w = tid >> 6;
  int lr = lane & 15, lg = lane >> 4;
  int sch = lane & 15, rsub = lane >> 4;

  const unsigned short* xb = xpack + (size_t)(off + m0) * H_DIM;
  const float* w1e = w1 + (size_t)e * (2 * I_DIM) * H_DIM;
  const float* r0 = w1e + (size_t)(nb * 64 + w * 16 + lr) * H_DIM + lg * 8;
  const float* r1 = r0 + (size_t)I_DIM * H_DIM;

  f32x4 acc0[8], acc1[8];
#pragma unroll
  for (int i = 0; i < 8; ++i) { acc0[i] = (f32x4){0,0,0,0}; acc1[i] = (f32x4){0,0,0,0}; }
  float4 P[4][4];

#define G1_DMA_A(PH, BUF)                                                       \
  { _Pragma("unroll") for (int j = 0; j < 8; ++j) {                             \
      int unit = j * 4 + w, row = unit * 4 + rsub;                              \
      int grr = (m0 + row < cnt) ? row : 0;                                     \
      dma16(xb + (size_t)grr * H_DIM + (PH) * 128 + (sch ^ (row & 7)) * 8,      \
            &AL[BUF][unit * 1024 + lane * 16]); }                               \
    SB(); }

#define G1_ISSUE(SL, KG)                                                        \
  { const float* q0 = r0 + (KG) * 32; const float* q1 = r1 + (KG) * 32;         \
    P[SL][0] = *(const float4*)q0; P[SL][1] = *(const float4*)(q0 + 4);         \
    P[SL][2] = *(const float4*)q1; P[SL][3] = *(const float4*)(q1 + 4);         \
    SB(); }

#define G1_USE(SL, BUF, KCL)                                                    \
  { union { unsigned u[4]; bf16x8 v; } bg, bu;                                  \
    bg.u[0] = cvt_pk_bf16(P[SL][0].x, P[SL][0].y);                              \
    bg.u[1] = cvt_pk_bf16(P[SL][0].z, P[SL][0].w);                              \
    bg.u[2] = cvt_pk_bf16(P[SL][1].x, P[SL][1].y);                              \
    bg.u[3] = cvt_pk_bf16(P[SL][1].z, P[SL][1].w);                              \
    bu.u[0] = cvt_pk_bf16(P[SL][2].x, P[SL][2].y);                              \
    bu.u[1] = cvt_pk_bf16(P[SL][2].z, P[SL][2].w);                              \
    bu.u[2] = cvt_pk_bf16(P[SL][3].x, P[SL][3].y);                              \
    bu.u[3] = cvt_pk_bf16(P[SL][3].z, P[SL][3].w);                              \
    _Pragma("unroll") for (int mr = 0; mr < 8; ++mr) {                          \
      int rowt = mr * 16 + lr;                                                  \
      bf16x8 a = *(const bf16x8*)&AL[BUF][rowt * 256 +                          \
                     ((((KCL) * 4 + lg) ^ (rowt & 7)) << 4)];                   \
      acc0[mr] = mfma16(a, bg.v, acc0[mr]);                                     \
      acc1[mr] = mfma16(a, bu.v, acc1[mr]); }                                   \
    SB(); }

  G1_DMA_A(0, 0);
  G1_ISSUE(0, 0) G1_ISSUE(1, 1) G1_ISSUE(2, 2) G1_ISSUE(3, 3)
  WAITVM16(); SB();
  __builtin_amdgcn_s_barrier();

#pragma unroll
  for (int ph = 0; ph < 8; ++ph) {
    int buf = ph & 1;
    if (ph < 7) G1_DMA_A(ph + 1, buf ^ 1);
#pragma unroll
    for (int kcl = 0; kcl < 4; ++kcl) {
      int kg = ph * 4 + kcl, sl = kg & 3;
      G1_USE(sl, buf, kcl);
      if (kg + 4 < 32) G1_ISSUE(sl, kg + 4);
    }
    if (ph < 7) { WAITVM16(); SB(); __builtin_amdgcn_s_barrier(); }
  }
#undef G1_DMA_A
#undef G1_ISSUE
#undef G1_USE

  // SwiGLU epilogue: lane col = gate/up row pair (same lr) -> act col
  int ncol = nb * 64 + w * 16 + lr;
#pragma unroll
  for (int mr = 0; mr < 8; ++mr) {
#pragma unroll
    for (int q = 0; q < 4; ++q) {
      int tok = mr * 16 + lg * 4 + q;
      if (m0 + tok < cnt) {
        float gv = acc0[mr][q];
        float av = gv / (1.0f + expf(-gv)) * acc1[mr][q];
        act[(size_t)(off + m0 + tok) * I_DIM + ncol] = f2bf(av);
      }
    }
  }
}

// ======================= GEMM2 (split-K x4) =======================
// block = 128 tok x 128 h-cols; K-chunk 1024 (8 phases of 128).
__global__ __launch_bounds__(256, 2)
void k_gemm2(const float* __restrict__ w2, const unsigned short* __restrict__ act,
             const int* __restrict__ counts, const float* __restrict__ row_w,
             float* __restrict__ yp) {
  int b = blockIdx.x;
  int nb = b & 7, mt = (b >> 3) & 7, q2 = b >> 6;   // grid 2048
  int e = q2 >> 2, kc = q2 & 3;
  int cnt = counts[e];
  int m0 = mt * 128;
  if (m0 >= cnt) return;
  int off = 0;
#pragma unroll
  for (int k = 0; k < NE; ++k) if (k < e) off += counts[k];
  int n0 = nb * 128;
  int kbase = kc * 1024;

  __shared__ __align__(16) unsigned char AL[2][32768];

  int tid = threadIdx.x, lane = tid & 63, w = tid >> 6;
  int lr = lane & 15, lg = lane >> 4;
  int sch = lane & 15, rsub = lane >> 4;

  const unsigned short* xb = act + (size_t)(off + m0) * I_DIM + kbase;
  const float* w2e = w2 + (size_t)e * H_DIM * I_DIM;
  const float* r0 = w2e + (size_t)(n0 + w * 16 + lr) * I_DIM + kbase + lg * 8;
  const float* r1 = r0 + (size_t)64 * I_DIM;

  f32x4 acc0[8], acc1[8];
#pragma unroll
  for (int i = 0; i < 8; ++i) { acc0[i] = (f32x4){0,0,0,0}; acc1[i] = (f32x4){0,0,0,0}; }
  float4 P[4][4];

#define G2_DMA_A(PH, BUF)                                                       \
  { _Pragma("unroll") for (int j = 0; j < 8; ++j) {                             \
      int unit = j * 4 + w, row = unit * 4 + rsub;                              \
      int grr = (m0 + row < cnt) ? row : 0;                                     \
      dma16(xb + (size_t)grr * I_DIM + (PH) * 128 + (sch ^ (row & 7)) * 8,      \
            &AL[BUF][unit * 1024 + lane * 16]); }                               \
    SB(); }

#define G2_ISSUE(SL, KG)                                                        \
  { const float* q0 = r0 + (KG) * 32; const float* q1 = r1 + (KG) * 32;         \
    P[SL][0] = *(const float4*)q0; P[SL][1] = *(const float4*)(q0 + 4);         \
    P[SL][2] = *(const float4*)q1; P[SL][3] = *(const float4*)(q1 + 4);         \
    SB(); }

#define G2_USE(SL, BUF, KCL)                                                    \
  { union { unsigned u[4]; bf16x8 v; } b0, b1;                                  \
    b0.u[0] = cvt_pk_bf16(P[SL][0].x, P[SL][0].y);                              \
    b0.u[1] = cvt_pk_bf16(P[SL][0].z, P[SL][0].w);                              \
    b0.u[2] = cvt_pk_bf16(P[SL][1].x, P[SL][1].y);                              \
    b0.u[3] = cvt_pk_bf16(P[SL][1].z, P[SL][1].w);                              \
    b1.u[0] = cvt_pk_bf16(P[SL][2].x, P[SL][2].y);                              \
    b1.u[1] = cvt_pk_bf16(P[SL][2].z, P[SL][2].w);                              \
    b1.u[2] = cvt_pk_bf16(P[SL][3].x, P[SL][3].y);                              \
    b1.u[3] = cvt_pk_bf16(P[SL][3].z, P[SL][3].w);                              \
    _Pragma("unroll") for (int mr = 0; mr < 8; ++mr) {                          \
      int rowt = mr * 16 + lr;                                                  \
      bf16x8 a = *(const bf16x8*)&AL[BUF][rowt * 256 +                          \
                     ((((KCL) * 4 + lg) ^ (rowt & 7)) << 4)];                   \
      acc0[mr] = mfma16(a, b0.v, acc0[mr]);                                     \
      acc1[mr] = mfma16(a, b1.v, acc1[mr]); }                                   \
    SB(); }

  G2_DMA_A(0, 0);
  G2_ISSUE(0, 0) G2_ISSUE(1, 1) G2_ISSUE(2, 2) G2_ISSUE(3, 3)
  WAITVM16(); SB();
  __builtin_amdgcn_s_barrier();

#pragma unroll
  for (int ph = 0; ph < 8; ++ph) {
    int buf = ph & 1;
    if (ph < 7) G2_DMA_A(ph + 1, buf ^ 1);
#pragma unroll
    for (int kcl = 0; kcl < 4; ++kcl) {
      int kg = ph * 4 + kcl, sl = kg & 3;
      G2_USE(sl, buf, kcl);
      if (kg + 4 < 32) G2_ISSUE(sl, kg + 4);
    }
    if (ph < 7) { WAITVM16(); SB(); __builtin_amdgcn_s_barrier(); }
  }
#undef G2_DMA_A
#undef G2_ISSUE
#undef G2_USE

  float* ypc = yp + (size_t)kc * (2048 * H_DIM);
  int c0 = n0 + w * 16 + lr;
#pragma unroll
  for (int mr = 0; mr < 8; ++mr) {
#pragma unroll
    for (int q = 0; q < 4; ++q) {
      int tok = mr * 16 + lg * 4 + q;
      if (m0 + tok >= cnt) continue;
      int grow = off + m0 + tok;
      float wgt = row_w[grow];
      float* yrow = ypc + (size_t)grow * H_DIM;
      yrow[c0] = acc0[mr][q] * wgt;
      yrow[c0 + 64] = acc1[mr][q] * wgt;
    }
  }
}

// ---------------- combine ----------------
__global__ void k_combine(const float* __restrict__ yp, const int* __restrict__ inv_row,
                          float* __restrict__ out) {
  int t = blockIdx.x, i = threadIdx.x;
  int r0 = inv_row[2 * t], r1 = inv_row[2 * t + 1];
  float4 s = make_float4(0.f, 0.f, 0.f, 0.f);
#pragma unroll
  for (int kc = 0; kc < 4; ++kc) {
    const float4* a = (const float4*)(yp + (size_t)kc * (2048 * H_DIM) + (size_t)r0 * H_DIM);
    const float4* b = (const float4*)(yp + (size_t)kc * (2048 * H_DIM) + (size_t)r1 * H_DIM);
    float4 va = a[i], vb = b[i];
    s.x += va.x + vb.x; s.y += va.y + vb.y; s.z += va.z + vb.z; s.w += va.w + vb.w;
  }
  ((float4*)(out + (size_t)t * H_DIM))[i] = s;
}

extern "C" void kernel_launch(void* const* d_in, const int* in_sizes, int n_in,
                              void* d_out, int out_size, void* d_ws, size_t ws_size,
                              hipStream_t stream) {
  const float* hs = (const float*)d_in[0];
  const float* w1 = (const float*)d_in[1];
  const float* w2 = (const float*)d_in[2];
  const float* gates = (const float*)d_in[3];
  float* out = (float*)d_out;

  char* ws = (char*)d_ws;
  int* counts = (int*)ws;
  int* tok_idx = (int*)(ws + 4096);
  float* tok_w = (float*)(ws + 4096 + 32768);
  int* tok_cpy = (int*)(ws + 4096 + 65536);
  float* row_w = (float*)(ws + 4096 + 98304);
  int* inv_row = (int*)(ws + 4096 + 98304 + 8192);
  unsigned short* xpack = (unsigned short*)(ws + (1 << 17));   // 4 MB
  unsigned short* act = (unsigned short*)(ws + (8u << 20));    // 16 MB
  float* yp = (float*)(ws + (32u << 20));                      // 4 x 8 MB

  (void)hipMemsetAsync(counts, 0, NE * sizeof(int), stream);
  k_route<<<dim3(4), dim3(256), 0, stream>>>(gates, counts, tok_idx, tok_w, tok_cpy);
  k_pack<<<dim3(NE * T_TOK), dim3(256), 0, stream>>>(hs, counts, tok_idx, tok_w, tok_cpy,
                                                     xpack, row_w, inv_row);
  k_gemm1<<<dim3(4096), dim3(256), 0, stream>>>(w1, xpack, counts, act);
  k_gemm2<<<dim3(2048), dim3(256), 0, stream>>>(w2, act, counts, row_w, yp);
  k_combine<<<dim3(T_TOK), dim3(256), 0, stream>>>(yp, inv_row, out);
}

// Round 10
// 226.077 us; speedup vs baseline: 2.4625x; 1.2500x over previous
//
#include <hip/hip_runtime.h>

#define T_TOK 1024
#define H_DIM 1024
#define I_DIM 4096
#define NE 8
#define NTF 20        // 320 tokens per pass
#define XSTR 40       // LDS row stride in shorts (80 B, pad kills bank conflicts)

typedef __attribute__((ext_vector_type(8))) short bf16x8;
typedef __attribute__((ext_vector_type(4))) float f32x4;
typedef __attribute__((ext_vector_type(8))) unsigned short us8;

__device__ __forceinline__ f32x4 mfma16(bf16x8 a, bf16x8 b, f32x4 c) {
  return __builtin_amdgcn_mfma_f32_16x16x32_bf16(a, b, c, 0, 0, 0);
}

__device__ __forceinline__ unsigned cvt_pk_bf16(float a, float b) {
  unsigned r;
  asm("v_cvt_pk_bf16_f32 %0, %1, %2" : "=v"(r) : "v"(a), "v"(b));
  return r;
}

// LDS-only sync: ds ops drained, vmem loads stay in flight
__device__ __forceinline__ void sync_lds() {
  asm volatile("s_waitcnt lgkmcnt(0)" ::: "memory");
  __builtin_amdgcn_s_barrier();
}

// ---------------- routing ----------------
__global__ void k_route(const float* __restrict__ gates, int* __restrict__ counts,
                        int* __restrict__ tok_idx, float* __restrict__ tok_w,
                        int* __restrict__ tok_cpy) {
  int t = blockIdx.x * blockDim.x + threadIdx.x;
  if (t >= T_TOK) return;
  float g[NE];
#pragma unroll
  for (int e = 0; e < NE; ++e) g[e] = gates[t * NE + e];
  int i1 = 0; float g1 = g[0];
#pragma unroll
  for (int e = 1; e < NE; ++e) if (g[e] > g1) { g1 = g[e]; i1 = e; }
  int i2 = -1; float g2 = -1e30f;
#pragma unroll
  for (int e = 0; e < NE; ++e) if (e != i1 && g[e] > g2) { g2 = g[e]; i2 = e; }
  float wa = 1.0f / (1.0f + expf(g2 - g1));
  float wb = 1.0f - wa;
  int s1 = atomicAdd(&counts[i1], 1);
  tok_idx[i1 * T_TOK + s1] = t; tok_w[i1 * T_TOK + s1] = wa; tok_cpy[i1 * T_TOK + s1] = 0;
  int s2 = atomicAdd(&counts[i2], 1);
  tok_idx[i2 * T_TOK + s2] = t; tok_w[i2 * T_TOK + s2] = wb; tok_cpy[i2 * T_TOK + s2] = 1;
}

// ---------------- pack ----------------
__global__ void k_pack(const float* __restrict__ hs, const int* __restrict__ counts,
                       const int* __restrict__ tok_idx, const float* __restrict__ tok_w,
                       const int* __restrict__ tok_cpy, unsigned short* __restrict__ xpack,
                       float* __restrict__ row_w, int* __restrict__ inv_row) {
  int e = blockIdx.x >> 10, slot = blockIdx.x & 1023;
  if (slot >= counts[e]) return;
  int off = 0;
#pragma unroll
  for (int i = 0; i < NE; ++i) if (i < e) off += counts[i];
  int row = off + slot;
  int tok = tok_idx[e * T_TOK + slot];
  if (threadIdx.x == 0) {
    row_w[row] = tok_w[e * T_TOK + slot];
    inv_row[tok * 2 + tok_cpy[e * T_TOK + slot]] = row;
  }
  float4 v = ((const float4*)(hs + (size_t)tok * H_DIM))[threadIdx.x];
  uint2 o; o.x = cvt_pk_bf16(v.x, v.y); o.y = cvt_pk_bf16(v.z, v.w);
  ((uint2*)(xpack + (size_t)row * H_DIM))[threadIdx.x] = o;
}

// ================ GEMM1: wave = 8 gate/up row-pairs x 320 tokens ================
// W: pure register stream (no LDS, no reuse). X: LDS double-buffered per 32-K chunk,
// reg-staged (T14), lgkm-only barriers. SwiGLU pairing via shfl_xor(32) at epilogue.
__global__ __launch_bounds__(256)
void k_gemm1(const float* __restrict__ w1, const unsigned short* __restrict__ xpack,
             const int* __restrict__ counts, unsigned short* __restrict__ act) {
  int b = blockIdx.x;                 // 1024 blocks; XCD = expert
  int e = b & 7, rb = b >> 3;         // rb in [0,128)
  int cnt = counts[e];
  int off = 0;
#pragma unroll
  for (int k = 0; k < NE; ++k) if (k < e) off += counts[k];

  __shared__ __align__(16) short XS[2][320 * XSTR];   // 2 x 25.6 KB

  int tid = threadIdx.x, lane = tid & 63, w = tid >> 6;
  int lt = lane & 15, lg = lane >> 4;
  int pbase = rb * 32 + w * 8;        // SwiGLU pair base for this wave
  // A-frag rows: 0-7 = gate rows pbase+., 8-15 = up rows I_DIM+pbase+.
  int arow = (lt < 8) ? (pbase + lt) : (I_DIM + pbase + (lt - 8));
  const float* wp0 = w1 + (size_t)e * (2 * I_DIM) * H_DIM + (size_t)arow * H_DIM + lg * 8;

  for (int tg = 0; tg < cnt; tg += 16 * NTF) {
    const unsigned short* ss[5];
    short* sd[5];
#pragma unroll
    for (int i = 0; i < 5; ++i) {
      int g = tid + 256 * i;          // 1280 16B-units: tok = g>>2, ku = g&3
      int stok = g >> 2, sku = g & 3;
      int row = off + tg + stok; if (row > 2047) row = 2047;
      ss[i] = xpack + (size_t)row * H_DIM + sku * 8;
      sd[i] = &XS[0][stok * XSTR + sku * 8];
    }
    f32x4 acc[NTF];
#pragma unroll
    for (int i = 0; i < NTF; ++i) acc[i] = (f32x4){0.f, 0.f, 0.f, 0.f};

    us8 xA[5], xB[5];
    float4 wA0, wA1, wB0, wB1;
#pragma unroll
    for (int i = 0; i < 5; ++i) xA[i] = *(const us8*)(ss[i]);        // X(0)
#pragma unroll
    for (int i = 0; i < 5; ++i) xB[i] = *(const us8*)(ss[i] + 32);   // X(1)
    wA0 = *(const float4*)(wp0);
    wA1 = *(const float4*)(wp0 + 4);
#pragma unroll
    for (int i = 0; i < 5; ++i) *(us8*)(sd[i]) = xA[i];              // X(0)->buf0

#pragma unroll
    for (int t = 0; t < 32; ++t) {
      sync_lds();                                    // X(t) visible in buf(t&1)
      // prefetch W(t+1)
      if (t + 1 < 32) {
        if ((t & 1) == 0) { wB0 = *(const float4*)(wp0 + (t + 1) * 32); wB1 = *(const float4*)(wp0 + (t + 1) * 32 + 4); }
        else              { wA0 = *(const float4*)(wp0 + (t + 1) * 32); wA1 = *(const float4*)(wp0 + (t + 1) * 32 + 4); }
      }
      // gather X(t+2) into the reg set just freed
      if (t + 2 < 32) {
        if ((t & 1) == 0) {
#pragma unroll
          for (int i = 0; i < 5; ++i) xA[i] = *(const us8*)(ss[i] + (t + 2) * 32);
        } else {
#pragma unroll
          for (int i = 0; i < 5; ++i) xB[i] = *(const us8*)(ss[i] + (t + 2) * 32);
        }
      }
      // write X(t+1) into buf^1
      if (t + 1 < 32) {
        if ((t & 1) == 0) {
#pragma unroll
          for (int i = 0; i < 5; ++i) *(us8*)(sd[i] + 320 * XSTR) = xB[i];
        } else {
#pragma unroll
          for (int i = 0; i < 5; ++i) *(us8*)(sd[i]) = xA[i];
        }
      }
      // compute chunk t
      union { unsigned u[4]; bf16x8 v; } af;
      float4 u0 = (t & 1) ? wB0 : wA0, u1 = (t & 1) ? wB1 : wA1;
      af.u[0] = cvt_pk_bf16(u0.x, u0.y); af.u[1] = cvt_pk_bf16(u0.z, u0.w);
      af.u[2] = cvt_pk_bf16(u1.x, u1.y); af.u[3] = cvt_pk_bf16(u1.z, u1.w);
      const short* xbase = &XS[t & 1][lt * XSTR + lg * 8];
#pragma unroll
      for (int tf = 0; tf < NTF; ++tf) {
        bf16x8 xf = *(const bf16x8*)(xbase + tf * (16 * XSTR));
        acc[tf] = mfma16(af.v, xf, acc[tf]);
      }
    }

    // SwiGLU epilogue: lanes lg<2 hold gate rows p=lg*4+q; up comes from lane+32
#pragma unroll
    for (int tf = 0; tf < NTF; ++tf) {
      int tok = tg + tf * 16 + lt;
#pragma unroll
      for (int q = 0; q < 4; q += 2) {
        float s0 = __shfl_xor(acc[tf][q], 32);
        float s1 = __shfl_xor(acc[tf][q + 1], 32);
        if (lg < 2 && tok < cnt) {
          float g0 = acc[tf][q],     a0 = g0 / (1.f + expf(-g0)) * s0;
          float g1 = acc[tf][q + 1], a1 = g1 / (1.f + expf(-g1)) * s1;
          unsigned pk = cvt_pk_bf16(a0, a1);
          *(unsigned*)(act + (size_t)(off + tok) * I_DIM + pbase + lg * 4 + q) = pk;
        }
      }
    }
  }
}

// ================ GEMM2: wave = 16 h-cols x 320 tokens, split-K x4 ================
__global__ __launch_bounds__(256)
void k_gemm2(const float* __restrict__ w2, const unsigned short* __restrict__ act,
             const int* __restrict__ counts, const float* __restrict__ row_w,
             float* __restrict__ yp) {
  int b = blockIdx.x;                 // 512 blocks; XCD = expert
  int e = b & 7, r = b >> 3;          // r in [0,64)
  int hb = r >> 2, kc = r & 3;
  int cnt = counts[e];
  int off = 0;
#pragma unroll
  for (int k = 0; k < NE; ++k) if (k < e) off += counts[k];

  __shared__ __align__(16) short XS[2][320 * XSTR];

  int tid = threadIdx.x, lane = tid & 63, w = tid >> 6;
  int lt = lane & 15, lg = lane >> 4;
  int hrow = hb * 64 + w * 16 + lt;   // w2 row (output h-col)
  const float* wp0 = w2 + (size_t)e * H_DIM * I_DIM + (size_t)hrow * I_DIM + kc * 1024 + lg * 8;

  for (int tg = 0; tg < cnt; tg += 16 * NTF) {
    const unsigned short* ss[5];
    short* sd[5];
#pragma unroll
    for (int i = 0; i < 5; ++i) {
      int g = tid + 256 * i;
      int stok = g >> 2, sku = g & 3;
      int row = off + tg + stok; if (row > 2047) row = 2047;
      ss[i] = act + (size_t)row * I_DIM + kc * 1024 + sku * 8;
      sd[i] = &XS[0][stok * XSTR + sku * 8];
    }
    f32x4 acc[NTF];
#pragma unroll
    for (int i = 0; i < NTF; ++i) acc[i] = (f32x4){0.f, 0.f, 0.f, 0.f};

    us8 xA[5], xB[5];
    float4 wA0, wA1, wB0, wB1;
#pragma unroll
    for (int i = 0; i < 5; ++i) xA[i] = *(const us8*)(ss[i]);
#pragma unroll
    for (int i = 0; i < 5; ++i) xB[i] = *(const us8*)(ss[i] + 32);
    wA0 = *(const float4*)(wp0);
    wA1 = *(const float4*)(wp0 + 4);
#pragma unroll
    for (int i = 0; i < 5; ++i) *(us8*)(sd[i]) = xA[i];

#pragma unroll
    for (int t = 0; t < 32; ++t) {
      sync_lds();
      if (t + 1 < 32) {
        if ((t & 1) == 0) { wB0 = *(const float4*)(wp0 + (t + 1) * 32); wB1 = *(const float4*)(wp0 + (t + 1) * 32 + 4); }
        else              { wA0 = *(const float4*)(wp0 + (t + 1) * 32); wA1 = *(const float4*)(wp0 + (t + 1) * 32 + 4); }
      }
      if (t + 2 < 32) {
        if ((t & 1) == 0) {
#pragma unroll
          for (int i = 0; i < 5; ++i) xA[i] = *(const us8*)(ss[i] + (t + 2) * 32);
        } else {
#pragma unroll
          for (int i = 0; i < 5; ++i) xB[i] = *(const us8*)(ss[i] + (t + 2) * 32);
        }
      }
      if (t + 1 < 32) {
        if ((t & 1) == 0) {
#pragma unroll
          for (int i = 0; i < 5; ++i) *(us8*)(sd[i] + 320 * XSTR) = xB[i];
        } else {
#pragma unroll
          for (int i = 0; i < 5; ++i) *(us8*)(sd[i]) = xA[i];
        }
      }
      union { unsigned u[4]; bf16x8 v; } af;
      float4 u0 = (t & 1) ? wB0 : wA0, u1 = (t & 1) ? wB1 : wA1;
      af.u[0] = cvt_pk_bf16(u0.x, u0.y); af.u[1] = cvt_pk_bf16(u0.z, u0.w);
      af.u[2] = cvt_pk_bf16(u1.x, u1.y); af.u[3] = cvt_pk_bf16(u1.z, u1.w);
      const short* xbase = &XS[t & 1][lt * XSTR + lg * 8];
#pragma unroll
      for (int tf = 0; tf < NTF; ++tf) {
        bf16x8 xf = *(const bf16x8*)(xbase + tf * (16 * XSTR));
        acc[tf] = mfma16(af.v, xf, acc[tf]);
      }
    }

    float* ypc = yp + (size_t)kc * (2048 * H_DIM);
#pragma unroll
    for (int tf = 0; tf < NTF; ++tf) {
      int tok = tg + tf * 16 + lt;
      if (tok < cnt) {
        float wgt = row_w[off + tok];
        float* yrow = ypc + (size_t)(off + tok) * H_DIM;
#pragma unroll
        for (int q = 0; q < 4; ++q)
          yrow[hb * 64 + w * 16 + lg * 4 + q] = acc[tf][q] * wgt;
      }
    }
  }
}

// ---------------- combine ----------------
__global__ void k_combine(const float* __restrict__ yp, const int* __restrict__ inv_row,
                          float* __restrict__ out) {
  int t = blockIdx.x, i = threadIdx.x;
  int r0 = inv_row[2 * t], r1 = inv_row[2 * t + 1];
  float4 s = make_float4(0.f, 0.f, 0.f, 0.f);
#pragma unroll
  for (int kc = 0; kc < 4; ++kc) {
    const float4* a = (const float4*)(yp + (size_t)kc * (2048 * H_DIM) + (size_t)r0 * H_DIM);
    const float4* b = (const float4*)(yp + (size_t)kc * (2048 * H_DIM) + (size_t)r1 * H_DIM);
    float4 va = a[i], vb = b[i];
    s.x += va.x + vb.x; s.y += va.y + vb.y; s.z += va.z + vb.z; s.w += va.w + vb.w;
  }
  ((float4*)(out + (size_t)t * H_DIM))[i] = s;
}

extern "C" void kernel_launch(void* const* d_in, const int* in_sizes, int n_in,
                              void* d_out, int out_size, void* d_ws, size_t ws_size,
                              hipStream_t stream) {
  const float* hs = (const float*)d_in[0];
  const float* w1 = (const float*)d_in[1];
  const float* w2 = (const float*)d_in[2];
  const float* gates = (const float*)d_in[3];
  float* out = (float*)d_out;

  char* ws = (char*)d_ws;
  int* counts = (int*)ws;
  int* tok_idx = (int*)(ws + 4096);
  float* tok_w = (float*)(ws + 4096 + 32768);
  int* tok_cpy = (int*)(ws + 4096 + 65536);
  float* row_w = (float*)(ws + 4096 + 98304);
  int* inv_row = (int*)(ws + 4096 + 98304 + 8192);
  unsigned short* xpack = (unsigned short*)(ws + (1 << 17));   // 4 MB
  unsigned short* act = (unsigned short*)(ws + (8u << 20));    // 16 MB
  float* yp = (float*)(ws + (32u << 20));                      // 4 x 8 MB

  (void)hipMemsetAsync(counts, 0, NE * sizeof(int), stream);
  k_route<<<dim3(4), dim3(256), 0, stream>>>(gates, counts, tok_idx, tok_w, tok_cpy);
  k_pack<<<dim3(NE * T_TOK), dim3(256), 0, stream>>>(hs, counts, tok_idx, tok_w, tok_cpy,
                                                     xpack, row_w, inv_row);
  k_gemm1<<<dim3(1024), dim3(256), 0, stream>>>(w1, xpack, counts, act);
  k_gemm2<<<dim3(512), dim3(256), 0, stream>>>(w2, act, counts, row_w, yp);
  k_combine<<<dim3(T_TOK), dim3(256), 0, stream>>>(yp, inv_row, out);
}